// Round 11
// baseline (170.872 us; speedup 1.0000x reference)
//
#include <hip/hip_runtime.h>
#include <hip/hip_bf16.h>

typedef float vf4 __attribute__((ext_vector_type(4)));

// Problem constants (SelfAttention decode step)
#define B_    32
#define DIM_  4096
#define TSEQ  2048
#define LASTT 2047
#define SCL   0.08838834764831845f   // 1/sqrt(128)
#define KCH   256            // 4096 / 16 K-chunks
#define ROWS1 6144
#define ROWS4 4096
#define RECF  4224           // cws floats per (b,chunk) record: 8g*4r*132

__device__ __forceinline__ float dotv(vf4 a, vf4 b) {
    return fmaf(a[0], b[0], fmaf(a[1], b[1], fmaf(a[2], b[2], a[3] * b[3])));
}

// ---------------------------------------------------------------------------
// Shared GEMM body (r3-measured config, byte-identical): tile = 128 rows x 32
// batches, K-chunk 256. Per-thread 4x4 micro-tile. Conflict-audited LDS.
// ---------------------------------------------------------------------------
__device__ __forceinline__ void gemm_tile_part(
    const float* __restrict__ W, const float* __restrict__ X,
    float* __restrict__ part, int rloc_base, int grow_base,
    int kb0, int kc, int rowsTot) {
    __shared__ __align__(16) vf4 wS[128][17];
    __shared__ __align__(16) vf4 xS[16][33];
    const int tid = threadIdx.x;
    const int rg = tid >> 3, bg = tid & 7;
    const int sr4 = tid >> 4, swf = tid & 15;
    const int sb = tid >> 3, sxf = tid & 7;
    float c[4][4] = {};

    for (int tile = 0; tile < 4; ++tile) {
        const int kb4 = (kb0 + tile * 64) >> 2;
        #pragma unroll
        for (int jj = 0; jj < 8; ++jj) {
            const int row = sr4 + 16 * jj;
            wS[row][swf] =
                ((const vf4*)(W + (size_t)(rloc_base + row) * DIM_))[kb4 + swf];
        }
        #pragma unroll
        for (int jj = 0; jj < 2; ++jj) {
            const int f4i = sxf + 8 * jj;
            xS[f4i][sb] = ((const vf4*)(X + (size_t)sb * DIM_))[kb4 + f4i];
        }
        __syncthreads();
        #pragma unroll
        for (int k4 = 0; k4 < 16; ++k4) {
            const vf4 w0 = wS[rg      ][k4];
            const vf4 w1 = wS[rg + 32 ][k4];
            const vf4 w2 = wS[rg + 64 ][k4];
            const vf4 w3 = wS[rg + 96 ][k4];
            const vf4 x0 = xS[k4][bg     ];
            const vf4 x1 = xS[k4][bg + 8 ];
            const vf4 x2 = xS[k4][bg + 16];
            const vf4 x3 = xS[k4][bg + 24];
            #pragma unroll
            for (int cm = 0; cm < 4; ++cm) {
                c[0][0] = fmaf(w0[cm], x0[cm], c[0][0]);
                c[0][1] = fmaf(w0[cm], x1[cm], c[0][1]);
                c[0][2] = fmaf(w0[cm], x2[cm], c[0][2]);
                c[0][3] = fmaf(w0[cm], x3[cm], c[0][3]);
                c[1][0] = fmaf(w1[cm], x0[cm], c[1][0]);
                c[1][1] = fmaf(w1[cm], x1[cm], c[1][1]);
                c[1][2] = fmaf(w1[cm], x2[cm], c[1][2]);
                c[1][3] = fmaf(w1[cm], x3[cm], c[1][3]);
                c[2][0] = fmaf(w2[cm], x0[cm], c[2][0]);
                c[2][1] = fmaf(w2[cm], x1[cm], c[2][1]);
                c[2][2] = fmaf(w2[cm], x2[cm], c[2][2]);
                c[2][3] = fmaf(w2[cm], x3[cm], c[2][3]);
                c[3][0] = fmaf(w3[cm], x0[cm], c[3][0]);
                c[3][1] = fmaf(w3[cm], x1[cm], c[3][1]);
                c[3][2] = fmaf(w3[cm], x2[cm], c[3][2]);
                c[3][3] = fmaf(w3[cm], x3[cm], c[3][3]);
            }
        }
        __syncthreads();
    }
    float* pb = part + (size_t)kc * rowsTot * 32;
    #pragma unroll
    for (int i = 0; i < 4; ++i)
        #pragma unroll
        for (int j = 0; j < 4; ++j)
            pb[(size_t)(grow_base + rg + 32 * i) * 32 + bg + 8 * j] = c[i][j];
}

// K1: QKV projection partials. Grid = 48 rowblocks x 16 K-chunks = 768.
__global__ __launch_bounds__(256) void k1_qkv(
    const float* __restrict__ x,  const float* __restrict__ wq,
    const float* __restrict__ wk, const float* __restrict__ wv,
    float* __restrict__ part) {
    const int rb = blockIdx.x >> 4, kc = blockIdx.x & 15;
    const int rbase = rb * 128;
    const float* W; int rloc;
    if (rbase < 4096)      { W = wq; rloc = rbase; }
    else if (rbase < 5120) { W = wk; rloc = rbase - 4096; }
    else                   { W = wv; rloc = rbase - 5120; }
    gemm_tile_part(W, x, part, rloc, rbase, kc * KCH, kc, ROWS1);
}

// K1b: sum 16 partials + RoPE + scatter. Grid = 384.
__global__ __launch_bounds__(256) void k1b_comb(
    const float* __restrict__ part, const float* __restrict__ fcos,
    const float* __restrict__ fsin, float* __restrict__ q_ws,
    float* __restrict__ k_ws, float* __restrict__ v_ws) {
    const int tid = threadIdx.x;
    const int b = tid & 31;
    const int row0 = (blockIdx.x * 8 + (tid >> 5)) * 2;
    float e = 0.f, o = 0.f;
    #pragma unroll
    for (int kc = 0; kc < 16; ++kc) {
        const float* pb = part + (size_t)kc * (ROWS1 * 32);
        e += pb[(size_t)row0 * 32 + b];
        o += pb[(size_t)(row0 + 1) * 32 + b];
    }
    if (row0 < 5120) {
        const int d = row0 & 127;
        const float cj = fcos[d >> 1], sj = fsin[d >> 1];
        const float re = e * cj - o * sj;
        const float ro = e * sj + o * cj;
        if (row0 < 4096) {
            q_ws[(size_t)b * 4096 + row0]     = re * SCL;
            q_ws[(size_t)b * 4096 + row0 + 1] = ro * SCL;
        } else {
            k_ws[(size_t)b * 1024 + row0 - 4096] = re;
            k_ws[(size_t)b * 1024 + row0 - 4095] = ro;
        }
    } else {
        v_ws[(size_t)b * 1024 + row0 - 5120] = e;
        v_ws[(size_t)b * 1024 + row0 - 5119] = o;
    }
}

// ---------------------------------------------------------------------------
// K2: flash attention partials, FULL-ROW consumption. Block = (b, 128-pos
// chunk); wave owns 32 positions for ALL 8 kv-heads (lane = (g = lane>>3,
// s = lane&7)). Per position t the wave's 4 load instrs consume the entire
// 4KB cache row [t][0:8][:] -- vs r3 where 8 different blocks each took 512B
// of the row (the hypothesized KV service-rate limiter). Instruction mix per
// (t,g) is identical to r3 (verified: 8 FMA, 1.5 shfl, 0.5 load per (t,g)).
// LDS p[8][4][129]: bank = (4g+r+t)%32 -> all score stores / stat reads /
// PV reads conflict-free. Position 2047 from k_ws/v_ws.
// ---------------------------------------------------------------------------
__global__ __launch_bounds__(256) void k2_attn(
    const float* __restrict__ q_ws, const float* __restrict__ k_ws,
    const float* __restrict__ v_ws, const float* __restrict__ cK,
    const float* __restrict__ cV,   float* __restrict__ cws) {
    __shared__ float p_lds[8][4][129];
    __shared__ __align__(16) float pacc[4][8][132];
    __shared__ float wred[4][32];
    __shared__ float wsum[4][32];
    __shared__ float mM[32];
    const int blk = blockIdx.x;               // b*16 + ch
    const int b = blk >> 4, ch = blk & 15;
    const int tid = threadIdx.x, wave = tid >> 6, lane = tid & 63;
    const int g = lane >> 3, s = lane & 7;
    const int tb = ch * 128 + wave * 32;      // wave's first position

    const vf4* qb4 = (const vf4*)(q_ws + ((size_t)b * 32 + g * 4) * 128);
    vf4 q4[4][4];
    #pragma unroll
    for (int r = 0; r < 4; ++r)
        #pragma unroll
        for (int j = 0; j < 4; ++j)
            q4[r][j] = qb4[r * 32 + j * 8 + s];

    const vf4* kwsrow = (const vf4*)(k_ws + ((size_t)b * 8 + g) * 128);
    const vf4* vwsrow = (const vf4*)(v_ws + ((size_t)b * 8 + g) * 128);

    // ---- score phase: 32 positions, 2-deep prefetch, full-row loads ----
    vf4 kb[4];
    {
        const int t = tb;
        const vf4* kr = (t == LASTT) ? kwsrow
            : (const vf4*)(cK + (((size_t)b * TSEQ + t) * 8 + g) * 128);
        #pragma unroll
        for (int j = 0; j < 4; ++j)
            kb[j] = __builtin_nontemporal_load(&kr[j * 8 + s]);
    }
    #pragma unroll 4
    for (int tt = 0; tt < 32; ++tt) {
        vf4 kn[4];
        if (tt < 31) {
            const int t = tb + tt + 1;
            const vf4* kr = (t == LASTT) ? kwsrow
                : (const vf4*)(cK + (((size_t)b * TSEQ + t) * 8 + g) * 128);
            #pragma unroll
            for (int j = 0; j < 4; ++j)
                kn[j] = __builtin_nontemporal_load(&kr[j * 8 + s]);
        }
        float a0 = 0.f, a1 = 0.f, a2 = 0.f, a3 = 0.f;
        #pragma unroll
        for (int j = 0; j < 4; ++j) {
            a0 += dotv(q4[0][j], kb[j]);
            a1 += dotv(q4[1][j], kb[j]);
            a2 += dotv(q4[2][j], kb[j]);
            a3 += dotv(q4[3][j], kb[j]);
        }
        #pragma unroll
        for (int m = 4; m >= 1; m >>= 1) {
            a0 += __shfl_xor(a0, m); a1 += __shfl_xor(a1, m);
            a2 += __shfl_xor(a2, m); a3 += __shfl_xor(a3, m);
        }
        const float val = (s == 0) ? a0 : (s == 1) ? a1 : (s == 2) ? a2 : a3;
        if (s < 4) p_lds[g][s][wave * 32 + tt] = val;
        #pragma unroll
        for (int j = 0; j < 4; ++j) kb[j] = kn[j];
    }

    // ---- wave-local stats over own region (in-wave DS ordering) ----
    const int pr_ = lane & 31, g2 = pr_ >> 2, r2 = pr_ & 3;
    float m = -3.4e38f;
    #pragma unroll 8
    for (int tt = 0; tt < 32; ++tt)
        m = fmaxf(m, p_lds[g2][r2][wave * 32 + tt]);
    float su = 0.f;
    #pragma unroll 8
    for (int tt = 0; tt < 32; ++tt)
        su += __expf(p_lds[g2][r2][wave * 32 + tt] - m);
    if (lane < 32) { wred[wave][pr_] = m; wsum[wave][pr_] = su; }
    __syncthreads();
    if (tid < 32) {
        float M = fmaxf(fmaxf(wred[0][tid], wred[1][tid]),
                        fmaxf(wred[2][tid], wred[3][tid]));
        float S = wsum[0][tid] * __expf(wred[0][tid] - M)
                + wsum[1][tid] * __expf(wred[1][tid] - M)
                + wsum[2][tid] * __expf(wred[2][tid] - M)
                + wsum[3][tid] * __expf(wred[3][tid] - M);
        mM[tid] = M;
        float* rec = cws + (size_t)blk * RECF + (tid >> 2) * 528 + (tid & 3) * 132;
        rec[128] = M;
        rec[129] = S;
    }
    __syncthreads();

    // ---- rewrite own region to exp(sc - M) ----
    #pragma unroll
    for (int i = 0; i < 16; ++i) {
        const int idx = i * 64 + lane;
        const int t5 = idx & 31, rr = (idx >> 5) & 3, gg = idx >> 7;
        const float v = p_lds[gg][rr][wave * 32 + t5];
        p_lds[gg][rr][wave * 32 + t5] = __expf(v - mM[(gg << 2) | rr]);
    }

    // ---- PV phase: 32 positions, 2-deep prefetch, full-row loads ----
    vf4 a[4][4];
    #pragma unroll
    for (int r = 0; r < 4; ++r)
        #pragma unroll
        for (int j = 0; j < 4; ++j)
            a[r][j] = (vf4){0.f, 0.f, 0.f, 0.f};
    vf4 vb[4];
    {
        const int t = tb;
        const vf4* vp = (t == LASTT) ? vwsrow
            : (const vf4*)(cV + (((size_t)b * TSEQ + t) * 8 + g) * 128);
        #pragma unroll
        for (int j = 0; j < 4; ++j)
            vb[j] = __builtin_nontemporal_load(&vp[j * 8 + s]);
    }
    #pragma unroll 4
    for (int tt = 0; tt < 32; ++tt) {
        vf4 vn[4];
        if (tt < 31) {
            const int t = tb + tt + 1;
            const vf4* vp = (t == LASTT) ? vwsrow
                : (const vf4*)(cV + (((size_t)b * TSEQ + t) * 8 + g) * 128);
            #pragma unroll
            for (int j = 0; j < 4; ++j)
                vn[j] = __builtin_nontemporal_load(&vp[j * 8 + s]);
        }
        #pragma unroll
        for (int r = 0; r < 4; ++r) {
            const float pw = p_lds[g][r][wave * 32 + tt];
            #pragma unroll
            for (int j = 0; j < 4; ++j)
                a[r][j] += pw * vb[j];
        }
        #pragma unroll
        for (int j = 0; j < 4; ++j) vb[j] = vn[j];
    }

    // ---- epilogue: cross-wave reduce via pacc, one r at a time ----
    float* recb = cws + (size_t)blk * RECF;
    #pragma unroll
    for (int r = 0; r < 4; ++r) {
        __syncthreads();
        #pragma unroll
        for (int j = 0; j < 4; ++j)
            *(vf4*)&pacc[wave][g][(j * 8 + s) * 4] = a[r][j];
        __syncthreads();
        for (int idx = tid; idx < 1024; idx += 256) {
            const int gg = idx >> 7, d = idx & 127;
            const float sum = pacc[0][gg][d] + pacc[1][gg][d]
                            + pacc[2][gg][d] + pacc[3][gg][d];
            recb[gg * 528 + r * 132 + d] = sum;
        }
    }
}

// K3: flash combine over 16 chunk records. Grid = 256 (b,g); wave = head r.
__global__ __launch_bounds__(256) void k3_comb(const float* __restrict__ cws,
                                               float* __restrict__ attn) {
    const int blk = blockIdx.x;       // b*8 + g
    const int b = blk >> 3, g = blk & 7;
    const int tid = threadIdx.x, r = tid >> 6, lane = tid & 63;
    const float* base0 = cws + (size_t)b * 16 * RECF + g * 528 + r * 132;
    float mi[16], si[16];
    float Mg = -3.4e38f;
    #pragma unroll
    for (int ci = 0; ci < 16; ++ci) {
        mi[ci] = base0[(size_t)ci * RECF + 128];
        si[ci] = base0[(size_t)ci * RECF + 129];
        Mg = fmaxf(Mg, mi[ci]);
    }
    float w[16], Sg = 0.f;
    #pragma unroll
    for (int ci = 0; ci < 16; ++ci) {
        w[ci] = __expf(mi[ci] - Mg);
        Sg = fmaf(si[ci], w[ci], Sg);
    }
    const float inv = 1.f / Sg;
    #pragma unroll
    for (int dd = 0; dd < 2; ++dd) {
        const int d = lane + dd * 64;
        float o = 0.f;
        #pragma unroll
        for (int ci = 0; ci < 16; ++ci)
            o = fmaf(base0[(size_t)ci * RECF + d], w[ci], o);
        attn[((size_t)b * 32 + g * 4 + r) * 128 + d] = o * inv;
    }
}

// K4: output projection partials. Grid = 32 rowblocks x 16 K-chunks = 512.
__global__ __launch_bounds__(256) void k4_out(
    const float* __restrict__ attn, const float* __restrict__ wo,
    float* __restrict__ part) {
    const int rb = blockIdx.x >> 4, kc = blockIdx.x & 15;
    const int rbase = rb * 128;
    gemm_tile_part(wo, attn, part, rbase, rbase, kc * KCH, kc, ROWS4);
}

// K4b: sum 16 partials -> out. Grid = 512.
__global__ __launch_bounds__(256) void k4b_comb(const float* __restrict__ part,
                                                float* __restrict__ out) {
    const int tid = threadIdx.x;
    const int b = tid & 31;
    const int row = blockIdx.x * 8 + (tid >> 5);
    float acc = 0.f;
    #pragma unroll
    for (int kc = 0; kc < 16; ++kc)
        acc += part[(size_t)kc * (ROWS4 * 32) + (size_t)row * 32 + b];
    out[(size_t)b * 4096 + row] = acc;
}

// ---------------------------------------------------------------------------
// Workspace (floats), region A reused serially (part1 -> cws -> part4):
//   A:    0          3,145,728  (max of 16*6144*32=3.15M, 512*4224=2.16M,
//                                16*4096*32=2.10M)
//   q_ws: 3,145,728    131,072
//   k_ws: 3,276,800     32,768
//   v_ws: 3,309,568     32,768
//   attn: 3,342,336    131,072   => ~13.9 MB total
// ---------------------------------------------------------------------------
extern "C" void kernel_launch(void* const* d_in, const int* in_sizes, int n_in,
                              void* d_out, int out_size, void* d_ws, size_t ws_size,
                              hipStream_t stream) {
    const float* x    = (const float*)d_in[0];
    const float* wq   = (const float*)d_in[1];
    const float* wk   = (const float*)d_in[2];
    const float* wv   = (const float*)d_in[3];
    const float* wo   = (const float*)d_in[4];
    const float* cK   = (const float*)d_in[5];
    const float* cV   = (const float*)d_in[6];
    const float* fcos = (const float*)d_in[7];
    const float* fsin = (const float*)d_in[8];
    float* ws   = (float*)d_ws;
    float* A    = ws;                    // part1 / cws / part4 (serial reuse)
    float* q_ws = ws + 3145728;
    float* k_ws = ws + 3276800;
    float* v_ws = ws + 3309568;
    float* attn = ws + 3342336;
    float* out  = (float*)d_out;

    hipLaunchKernelGGL(k1_qkv,   dim3(768),  dim3(256), 0, stream,
                       x, wq, wk, wv, A);
    hipLaunchKernelGGL(k1b_comb, dim3(384),  dim3(256), 0, stream,
                       A, fcos, fsin, q_ws, k_ws, v_ws);
    hipLaunchKernelGGL(k2_attn,  dim3(512),  dim3(256), 0, stream,
                       q_ws, k_ws, v_ws, cK, cV, A);
    hipLaunchKernelGGL(k3_comb,  dim3(256),  dim3(256), 0, stream, A, attn);
    hipLaunchKernelGGL(k4_out,   dim3(512),  dim3(256), 0, stream, attn, wo, A);
    hipLaunchKernelGGL(k4b_comb, dim3(512),  dim3(256), 0, stream, A, out);
}